// Round 6
// baseline (75.507 us; speedup 1.0000x reference)
//
#include <hip/hip_runtime.h>

#define NB 16
#define NT 50
#define NA 5
#define NH 152
#define NW 152
#define CH 70             // NA*(7+NC)
#define HW (NH*NW)        // 23104
#define AHW (NA*HW)       // 115520
#define NCELL (NB*AHW)    // 1,848,320
#define NTGT (NB*NT)      // 800

#define NSUMB 452
#define SUM_IT 4          // 452*256*4*4 >= NCELL (bounds-checked)
#define GRID_FUSED (NSUMB + NTGT + NTGT + 1)   // 2053

// ws float layout (private per-block slots, no atomics anywhere)
#define S_SUM 0                     // 452 floats: softplus grand-total partials
#define S_SUB 452                   // 801 floats: excluded-cell softplus sums
#define S_CNT (S_SUB + 801)         // 801 floats: excluded-cell counts
#define S_WIN (S_CNT + 801)         // 801 x 8 floats: winner loss terms
#define WS_FLOATS (S_WIN + 801*8)   // 8462 floats ~ 34 KB

__device__ __forceinline__ float sp_f(float v) {
    return (v > 20.f) ? v : __logf(1.f + __expf(v));
}

struct CB { float xlo, xhi, ylo, yhi, w, h, qb, l6; };

// __noinline__: exactly ONE codegen instance so the exclusion predicate is
// bit-identical across all blocks (ownership dedup requires this).
__device__ __noinline__ CB make_cb(const float* __restrict__ x,
                                   const float* __restrict__ anc,
                                   int b, int a, int j, int i) {
    const float* xp = x + (size_t)(b * CH + a * 14) * HW + j * NW + i;
    float l0 = xp[0], l1 = xp[HW], l2 = xp[2 * HW], l3 = xp[3 * HW], l6 = xp[6 * HW];
    float aw = anc[2 * a], ah = anc[2 * a + 1];
    float bx = (float)i + 1.f / (1.f + __expf(-l0));
    float by = (float)j + 1.f / (1.f + __expf(-l1));
    float bw = __expf(l2) * aw, bh = __expf(l3) * ah;
    CB c;
    c.xlo = bx - 0.5f * bw; c.xhi = bx + 0.5f * bw;
    c.ylo = by - 0.5f * bh; c.yhi = by + 0.5f * bh;
    c.w = bw; c.h = bh; c.qb = 0.375f * bw * bh; c.l6 = l6;
    return c;
}

__device__ __noinline__ int iou_hit(CB c, float xlo, float xhi, float ylo, float yhi,
                                    float gw, float gl, float q) {
    float mx = fminf(c.xlo, xlo), Mx = fmaxf(c.xhi, xhi);
    float my = fminf(c.ylo, ylo), My = fmaxf(c.yhi, yhi);
    float cw = c.w + gw - (Mx - mx), ch = c.h + gl - (My - my);
    // iou > 0.6  <=>  carea > 0.375*(area_b + area_g)
    return (cw > 0.f && ch > 0.f && cw * ch > c.qb + q) ? 1 : 0;
}

__device__ __forceinline__ void win_terms(const float* __restrict__ xp,
                                          float tx, float ty, float twv, float tlv,
                                          float timv, float trev, int lab,
                                          float* __restrict__ o) {
    float l[14];
    #pragma unroll
    for (int c = 0; c < 14; ++c) l[c] = xp[c * HW];
    float px = 1.f / (1.f + __expf(-l[0]));
    float py = 1.f / (1.f + __expf(-l[1]));
    o[0] = (px - tx) * (px - tx);
    o[1] = (py - ty) * (py - ty);
    float dw = l[2] - twv; o[2] = dw * dw;
    float dh = l[3] - tlv; o[3] = dh * dh;
    float di = l[4] - timv, dr = l[5] - trev;
    o[4] = di * di + dr * dr;
    o[5] = sp_f(-l[6]);
    float mx = l[7];
    #pragma unroll
    for (int c = 8; c < 14; ++c) mx = fmaxf(mx, l[c]);
    float e[7], se = 0.f;
    #pragma unroll
    for (int c = 0; c < 7; ++c) { e[c] = __expf(l[7 + c] - mx); se += e[c]; }
    float s[7], se2 = 0.f;
    #pragma unroll
    for (int c = 0; c < 7; ++c) { s[c] = e[c] / se; se2 += __expf(s[c]); }
    o[6] = __logf(se2) - s[lab];
    o[7] = 1.f;
}

__global__ void __launch_bounds__(256) k_fused(const float* __restrict__ x,
                                               const float* __restrict__ tgt,
                                               const float* __restrict__ anc,
                                               float* __restrict__ ws) {
    __shared__ float s_gx[NT], s_gy[NT], s_gw[NT], s_gl[NT];
    __shared__ float s_xlo[NT], s_xhi[NT], s_ylo[NT], s_yhi[NT], s_q[NT];
    __shared__ float s_tim[NT], s_tre[NT], s_tw[NT], s_tl[NT];
    __shared__ int s_nz[NT], s_valid[NT], s_validp[NT];
    __shared__ int s_gi[NT], s_gj[NT], s_bn[NT], s_am[NT], s_lab[NT];
    __shared__ float redA[256], redB[256];
    __shared__ int s_flag;

    int tid = threadIdx.x, bx = blockIdx.x;

    // ---------------- role: unmasked grand softplus(l6) sum ----------------
    if (bx < NSUMB) {
        float s = 0.f;
        #pragma unroll
        for (int it = 0; it < SUM_IT; ++it) {
            int c4 = (((it * NSUMB + bx) * 256) + tid) * 4;
            if (c4 < NCELL) {
                int b = c4 / AHW;
                int within = c4 - b * AHW;
                int a = within / HW;
                int rem = within - a * HW;
                const float* p = x + (size_t)(b * CH + a * 14 + 6) * HW + rem;
                float4 v = *(const float4*)p;
                s += sp_f(v.x) + sp_f(v.y) + sp_f(v.z) + sp_f(v.w);
            }
        }
        redA[tid] = s;
        __syncthreads();
        for (int st = 128; st > 0; st >>= 1) {
            if (tid < st) redA[tid] += redA[tid + st];
            __syncthreads();
        }
        if (tid == 0) ws[S_SUM + bx] = redA[0];
        return;
    }

    // ---------------- phase A (single textual site): batch descriptors ----
    int b;
    if (bx < NSUMB + NTGT) b = (bx - NSUMB) / NT;
    else if (bx < NSUMB + 2 * NTGT) b = (bx - NSUMB - NTGT) / NT;
    else b = NB - 1;

    if (tid < NT) {
        const float* tp = tgt + (size_t)(b * NT + tid) * 7;
        float lab = tp[0], cx = tp[1], cy = tp[2], w7 = tp[3], l7 = tp[4];
        float ti = tp[5], tr = tp[6];
        s_nz[tid] = (cx != 0.f) ? 1 : 0;
        s_valid[tid] = ((lab + cx + cy + w7 + l7 + ti + tr) != 0.f) ? 1 : 0;
        float gx = cx * NW, gy = cy * NH, gw = w7 * NW, gl = l7 * NH;
        s_gx[tid] = gx; s_gy[tid] = gy; s_gw[tid] = gw; s_gl[tid] = gl;
        s_xlo[tid] = gx - 0.5f * gw; s_xhi[tid] = gx + 0.5f * gw;
        s_ylo[tid] = gy - 0.5f * gl; s_yhi[tid] = gy + 0.5f * gl;
        s_q[tid] = 0.375f * gw * gl;
        s_gi[tid] = min(max((int)gx, 0), NW - 1);
        s_gj[tid] = min(max((int)gy, 0), NH - 1);
        float agt = (gw + 1.f) * (gl + 1.f);
        float best = -1.f; int bn = 0, am = 0;
        float awb = 1.f, ahb = 1.f;
        for (int a = 0; a < NA; ++a) {
            float aw = anc[2 * a], ah = anc[2 * a + 1];
            float iw = fmaxf(fminf(gw, aw) + 1.f, 0.f);
            float ih = fmaxf(fminf(gl, ah) + 1.f, 0.f);
            float inter = iw * ih;
            float aan = (aw + 1.f) * (ah + 1.f);
            float iou = inter / (agt + aan - inter + 1e-16f);
            if (iou > best) { best = iou; bn = a; awb = aw; ahb = ah; }
            if (iou > 0.6f) am |= (1 << a);
        }
        s_bn[tid] = bn; s_am[tid] = am;
        s_tw[tid] = logf(gw / awb + 1e-16f);
        s_tl[tid] = logf(gl / ahb + 1e-16f);
        s_tim[tid] = ti; s_tre[tid] = tr;
        s_lab[tid] = ((int)lab) & 7;
    }
    __syncthreads();
    if (tid < NT) {
        int vp = 1;
        for (int u = 0; u <= tid; ++u) vp &= s_nz[u];
        s_validp[tid] = vp;
    }
    __syncthreads();

    // exclusion predicate E_u(cell): integer part exact; float part via the
    // single-instance noinline iou_hit -> bit-identical across blocks.
    auto e_u = [&](const CB& cb, int i, int j, int a, int u) -> bool {
        if (s_valid[u] && i == s_gi[u] && j == s_gj[u] &&
            (a == s_bn[u] || ((s_am[u] >> a) & 1))) return true;
        if (s_validp[u] && s_gw[u] > 0.f && s_gl[u] > 0.f &&
            iou_hit(cb, s_xlo[u], s_xhi[u], s_ylo[u], s_yhi[u],
                    s_gw[u], s_gl[u], s_q[u])) return true;
        return false;
    };

    if (bx < NSUMB + NTGT) {
        // ---------------- role: owner-subtract (per target) ----------------
        int w = bx - NSUMB;
        int t = w - b * NT;
        float sub = 0.f; float cnt = 0.f;
        int i_lo = 1, i_hi = 0, j_lo = 1, j_hi = 0;   // empty sentinel
        bool vp = s_validp[t] && s_gw[t] > 0.f && s_gl[t] > 0.f;
        if (vp) {
            // proven reach: IoU pass => |bx-gx| < gw/3, |by-gy| < gl/3 (+1 margin)
            float gw3 = s_gw[t] * (1.f / 3.f), gl3 = s_gl[t] * (1.f / 3.f);
            i_lo = max(0, (int)floorf(s_gx[t] - gw3) - 1);
            i_hi = min(NW - 1, (int)floorf(s_gx[t] + gw3) + 1);
            j_lo = max(0, (int)floorf(s_gy[t] - gl3) - 1);
            j_hi = min(NH - 1, (int)floorf(s_gy[t] + gl3) + 1);
            int W = i_hi - i_lo + 1, Hh = j_hi - j_lo + 1;
            int total = W * Hh * NA;
            for (int idx = tid; idx < total; idx += 256) {
                int dx = idx % W;
                int q2 = idx / W;
                int j = j_lo + q2 % Hh;
                int a = q2 / Hh;
                int i = i_lo + dx;
                CB cb = make_cb(x, anc, b, a, j, i);
                if (e_u(cb, i, j, a, t)) {
                    bool own = true;
                    for (int u = 0; u < t; ++u)
                        if (e_u(cb, i, j, a, u)) { own = false; break; }
                    if (own) { sub += sp_f(cb.l6); cnt += 1.f; }
                }
            }
        }
        // override cells not covered by the rect scan (e.g. valid && !validp)
        if (tid == 0 && s_valid[t]) {
            int gi = s_gi[t], gj = s_gj[t];
            for (int a = 0; a < NA; ++a) {
                if (a == s_bn[t] || ((s_am[t] >> a) & 1)) {
                    bool inRect = vp && gi >= i_lo && gi <= i_hi && gj >= j_lo && gj <= j_hi;
                    if (!inRect) {
                        CB cb = make_cb(x, anc, b, a, gj, gi);
                        bool own = true;
                        for (int u = 0; u < t; ++u)
                            if (e_u(cb, gi, gj, a, u)) { own = false; break; }
                        if (own) { sub += sp_f(cb.l6); cnt += 1.f; }
                    }
                }
            }
        }
        redA[tid] = sub; redB[tid] = cnt;
        __syncthreads();
        for (int st = 128; st > 0; st >>= 1) {
            if (tid < st) { redA[tid] += redA[tid + st]; redB[tid] += redB[tid + st]; }
            __syncthreads();
        }
        if (tid == 0) { ws[S_SUB + w] = redA[0]; ws[S_CNT + w] = redB[0]; }
    } else if (bx < NSUMB + 2 * NTGT) {
        // ---------------- role: winner eval (per target, dedup'd) ----------
        int w = bx - NSUMB - NTGT;
        int t = w - b * NT;
        if (tid == 0) s_flag = 0;
        __syncthreads();
        if (s_valid[t]) {
            int key = s_gi[t] | (s_gj[t] << 8) | (s_bn[t] << 16);
            int t2 = t + 1 + tid;
            if (t2 < NT && s_valid[t2]) {
                int k2 = s_gi[t2] | (s_gj[t2] << 8) | (s_bn[t2] << 16);
                if (k2 == key) s_flag = 1;   // benign race, monotone
            }
        }
        __syncthreads();
        if (tid == 0) {
            float slot[8] = {0.f, 0.f, 0.f, 0.f, 0.f, 0.f, 0.f, 0.f};
            if (s_valid[t] && !s_flag) {     // last-t-wins (np scatter order)
                const float* xp = x + (size_t)(b * CH + s_bn[t] * 14) * HW
                                  + s_gj[t] * NW + s_gi[t];
                win_terms(xp, s_gx[t] - (float)s_gi[t], s_gy[t] - (float)s_gj[t],
                          s_tw[t], s_tl[t], s_tim[t], s_tre[t], s_lab[t], slot);
            }
            float* dst = ws + S_WIN + w * 8;
            #pragma unroll
            for (int k = 0; k < 8; ++k) dst[k] = slot[k];
        }
    } else {
        // ---------------- role: c* (np negative-index wrap cell) -----------
        if (tid == 0) s_flag = 0;
        __syncthreads();
        for (int id = tid; id < NTGT; id += 256) {
            const float* tp = tgt + (size_t)id * 7;
            float s7 = tp[0] + tp[1] + tp[2] + tp[3] + tp[4] + tp[5] + tp[6];
            if (s7 == 0.f) s_flag = 1;       // any invalid row -> wrap exists
        }
        __syncthreads();
        if (tid == 0) {
            float slot[8] = {0.f, 0.f, 0.f, 0.f, 0.f, 0.f, 0.f, 0.f};
            float sub = 0.f, cnt = 0.f;
            if (s_flag) {
                // winner values from an all-zero row: tx=ty=tim=tre=0,
                // tw=tl=log(1e-16), best_n=0 -> label 0
                const float* xp = x + (size_t)((NB - 1) * CH + (NA - 1) * 14) * HW
                                  + (HW - 1);
                float L16 = logf(1e-16f);
                win_terms(xp, 0.f, 0.f, L16, L16, 0.f, 0.f, 0, slot);
                // subtract c* from the negative-conf sum unless some batch-15
                // target already excludes it (then its owner subtracted it)
                CB cb = make_cb(x, anc, NB - 1, NA - 1, NH - 1, NW - 1);
                bool excl = false;
                for (int u = 0; u < NT; ++u)
                    if (e_u(cb, NW - 1, NH - 1, NA - 1, u)) { excl = true; break; }
                if (!excl) { sub = sp_f(cb.l6); cnt = 1.f; }
            }
            float* dst = ws + S_WIN + NTGT * 8;
            #pragma unroll
            for (int k = 0; k < 8; ++k) dst[k] = slot[k];
            ws[S_SUB + NTGT] = sub;
            ws[S_CNT + NTGT] = cnt;
        }
    }
}

// ---------------- tiny deterministic reduce + loss assembly ----------------
__global__ void __launch_bounds__(256) k_reduce2(const float* __restrict__ ws,
                                                 float* __restrict__ out) {
    int tid = threadIdx.x;
    double acc[11];
    #pragma unroll
    for (int k = 0; k < 11; ++k) acc[k] = 0.0;
    for (int s = tid; s < NTGT + 1; s += 256) {
        const float* p = ws + S_WIN + s * 8;
        #pragma unroll
        for (int k = 0; k < 8; ++k) acc[k] += (double)p[k];
        acc[8] += (double)ws[S_SUB + s];
        acc[9] += (double)ws[S_CNT + s];
    }
    for (int s = tid; s < NSUMB; s += 256) acc[10] += (double)ws[S_SUM + s];

    __shared__ double R[11][256];
    #pragma unroll
    for (int k = 0; k < 11; ++k) R[k][tid] = acc[k];
    __syncthreads();
    for (int st = 128; st > 0; st >>= 1) {
        if (tid < st) {
            #pragma unroll
            for (int k = 0; k < 11; ++k) R[k][tid] += R[k][tid + st];
        }
        __syncthreads();
    }
    if (tid == 0) {
        double nM  = fmax(R[7][0], 1.0);
        double scf = fmax((double)NCELL - R[9][0], 1.0);
        double bce = R[10][0] - R[8][0];
        double loss =
            (R[0][0] + R[1][0] + R[2][0] + R[3][0] + R[4][0] + R[5][0]) / nM
            + bce / scf
            + (1.0 / NB) * R[6][0] / nM;
        out[0] = (float)loss;
    }
}

extern "C" void kernel_launch(void* const* d_in, const int* in_sizes, int n_in,
                              void* d_out, int out_size, void* d_ws, size_t ws_size,
                              hipStream_t stream) {
    const float* x   = (const float*)d_in[0];
    const float* tgt = (const float*)d_in[1];
    const float* anc = (const float*)d_in[2];
    float* ws  = (float*)d_ws;
    float* out = (float*)d_out;

    hipLaunchKernelGGL(k_fused, dim3(GRID_FUSED), dim3(256), 0, stream,
                       x, tgt, anc, ws);
    hipLaunchKernelGGL(k_reduce2, dim3(1), dim3(256), 0, stream, ws, out);
}